// Round 18
// baseline (192.760 us; speedup 1.0000x reference)
//
#include <hip/hip_runtime.h>
#include <hip/hip_bf16.h>

// ---------------- constants ----------------
#define EPS 1e-6f
#define NBH 32      // B*H
#define LSEQ 1024
#define DHD 64

typedef unsigned short u16;
typedef __bf16 bf16x8 __attribute__((ext_vector_type(8)));
typedef float f32x4 __attribute__((ext_vector_type(4)));

__device__ inline u16 f2bf(float f){
  union { float f; unsigned u; } un; un.f = f;
  unsigned u = un.u;
  u += 0x7fffu + ((u >> 16) & 1u);
  return (u16)(u >> 16);
}

__device__ inline float bf2f(u16 v){
  union { unsigned u; float f; } un; un.u = ((unsigned)v) << 16; return un.f;
}

__device__ inline float wred64(float v){
#pragma unroll
  for (int off = 32; off > 0; off >>= 1) v += __shfl_xor(v, off, 64);
  return v;
}

__device__ inline float wscan64(float v, int lane){
  float run = v;
#pragma unroll
  for (int off = 1; off < 64; off <<= 1){
    float t = __shfl_up(run, off, 64);
    if (lane >= off) run += t;
  }
  return run;   // inclusive
}

__device__ inline float fast_sigmoid(float x){
  return 1.f / (1.f + __expf(-x));
}

__device__ inline void gload_lds16(const u16* g, u16* l){
  __builtin_amdgcn_global_load_lds(
      (const __attribute__((address_space(1))) unsigned int*)g,
      (__attribute__((address_space(3))) unsigned int*)l, 16, 0, 0);
}

// accumulate 8 bf16 packed in a uint4 into a[0..7]
__device__ inline void acc8(float* a, uint4 w){
  a[0] += bf2f((u16)(w.x & 0xffff)); a[1] += bf2f((u16)(w.x >> 16));
  a[2] += bf2f((u16)(w.y & 0xffff)); a[3] += bf2f((u16)(w.y >> 16));
  a[4] += bf2f((u16)(w.z & 0xffff)); a[5] += bf2f((u16)(w.z >> 16));
  a[6] += bf2f((u16)(w.w & 0xffff)); a[7] += bf2f((u16)(w.w >> 16));
}

// ---------------- mega prep kernel (f2bf + 6 transposes + bias + zero) -------
__device__ inline void tr_tile2(const float* in, u16* out, int R, int C, int r0, int c0){
  __shared__ float tile[32][33];
  int x = threadIdx.x & 31, y = threadIdx.x >> 5;
#pragma unroll
  for (int j = 0; j < 4; j++)
    tile[y + j*8][x] = in[(size_t)(r0 + y + j*8) * C + c0 + x];
  __syncthreads();
#pragma unroll
  for (int j = 0; j < 4; j++)
    out[(size_t)(c0 + y + j*8) * R + r0 + x] = f2bf(tile[x][y + j*8]);
}

// blocks: [0,2048) f2bf inputs; [2048,6144) Wq/Wk/Wv/Wo transposes;
// [6144,14336) W1/W2 transposes; [14336,14348) bias gather;
// [14348,14412) zero ckb||cqb (contiguous 256KB)
__global__ __launch_bounds__(256) void prep_all(
    const float* __restrict__ inputs, u16* __restrict__ Xbf,
    const float* __restrict__ Wq, const float* __restrict__ Wk,
    const float* __restrict__ Wv, const float* __restrict__ Wo,
    u16* __restrict__ dqkv, u16* __restrict__ dwo,
    const float* __restrict__ W1, const float* __restrict__ W2,
    u16* __restrict__ d1, u16* __restrict__ d2,
    const float* __restrict__ bq, const float* __restrict__ bk,
    const float* __restrict__ bv, float* __restrict__ bqkv,
    float* __restrict__ ckq_zero)
{
  int b = blockIdx.x;
  if (b < 2048){
    int i = b * 256 + threadIdx.x;
    float4 v = reinterpret_cast<const float4*>(inputs)[i];
    ushort4 o; o.x = f2bf(v.x); o.y = f2bf(v.y); o.z = f2bf(v.z); o.w = f2bf(v.w);
    reinterpret_cast<ushort4*>(Xbf)[i] = o;
  } else if (b < 6144){
    int t = b - 2048;
    int z = t >> 10, rem = t & 1023;
    int bx = rem & 31, by = rem >> 5;
    const float* in = (z == 0) ? Wq : (z == 1) ? Wk : (z == 2) ? Wv : Wo;
    u16* out = (z < 3) ? (dqkv + (size_t)z * 1024 * 1024) : dwo;
    tr_tile2(in, out, 1024, 1024, by * 32, bx * 32);
  } else if (b < 14336){
    int t = b - 6144;
    int z = t >> 12, rem = t & 4095;
    int bx = rem & 127, by = rem >> 7;
    if (z == 0) tr_tile2(W1, d1, 1024, 4096, by * 32, bx * 32);
    else        tr_tile2(W2, d2, 4096, 1024, bx * 32, by * 32);
  } else if (b < 14348){
    int i = (b - 14336) * 256 + threadIdx.x;
    if (i < 3072){
      float v = (i < 1024) ? bq[i] : (i < 2048) ? bk[i - 1024] : bv[i - 2048];
      bqkv[i] = v;
    }
  } else {
    int i = (b - 14348) * 256 + threadIdx.x;
    reinterpret_cast<float4*>(ckq_zero)[i] = make_float4(0.f, 0.f, 0.f, 0.f);
  }
}

// ---------------- bf16 MFMA GEMM (dbuf + counted vmcnt, T2 XOR-swizzled LDS) ----
// C[M,N] = act(A[M,K] @ Bt[N,K]^T + bias)
// LDS: BK=64 bf16 rows = 8 x 16B slots; slot s of row r at phys slot s^(r&7)
// (rule #21: linear gload_lds dest + pre-swizzled SOURCE + swizzled READ).
// Pipeline: STAGE(next) before compute(cur); counted vmcnt across the barrier.
// ACT: 0 none, 2 gelu  (OM==1 applies fast sigmoid for col<2048 internally)
// OM: 1 fused-QKV bf16 remap to 3x[B,H,L,DH] + chunk-sum atomics into cq/ck;
//     3 bf16 [M][N]; 4 raw f32 partial (slice z at outF + z*M*N);
//     5 bf16 partial (slice z at outB + z*M*N)
template<int BM, int BN, int ACT, int OM>
__global__ __launch_bounds__(256) void gemm_mfma(
    const u16* __restrict__ A, const u16* __restrict__ Bt,
    const float* __restrict__ bias, const float* __restrict__ resid,
    float* __restrict__ outF, u16* __restrict__ outB,
    float* __restrict__ cqA, float* __restrict__ ckA,
    int M, int N, int K)
{
  constexpr int BK = 64;
  constexpr int MI = BM / 32;
  constexpr int NJ = BN / 32;
  constexpr int RA = BM / 32;
  constexpr int RB = BN / 32;
  constexpr int NS = RA + RB;
  __shared__ u16 As[2][BM * BK];
  __shared__ u16 Bs[2][BN * BK];
  const int tid = threadIdx.x;
  const int lane = tid & 63, wave = tid >> 6;
  const int lrow = lane & 15, lg = lane >> 4;
  const int m0 = blockIdx.x * BM, n0 = blockIdx.y * BN;
  const int wm = (wave >> 1) * (BM / 2), wn = (wave & 1) * (BN / 2);

  const int ksz = K / gridDim.z;
  const int k_begin = blockIdx.z * ksz;
  const int k_end = k_begin + ksz;

  f32x4 acc[MI][NJ];
#pragma unroll
  for (int i = 0; i < MI; i++)
#pragma unroll
    for (int j = 0; j < NJ; j++) acc[i][j] = (f32x4){0.f, 0.f, 0.f, 0.f};

  const u16* Ab = A + (size_t)m0 * K;
  const u16* Bb = Bt + (size_t)n0 * K;

  const int s0 = ((0 * 4 + lg) ^ (lrow & 7)) * 8;
  const int s1 = ((1 * 4 + lg) ^ (lrow & 7)) * 8;

  auto STAGE = [&](int buf, int k0){
#pragma unroll
    for (int r = 0; r < RA; ++r){
      int c = r * 256 + tid;
      int row = c >> 3;
      int kk = ((c ^ row) & 7) << 3;
      gload_lds16(Ab + (size_t)row * K + k0 + kk, &As[buf][(r * 256 + wave * 64) * 8]);
    }
#pragma unroll
    for (int r = 0; r < RB; ++r){
      int c = r * 256 + tid;
      int row = c >> 3;
      int kk = ((c ^ row) & 7) << 3;
      gload_lds16(Bb + (size_t)row * K + k0 + kk, &Bs[buf][(r * 256 + wave * 64) * 8]);
    }
  };

  STAGE(0, k_begin);
  int cur = 0;
  for (int k0 = k_begin; k0 < k_end; k0 += BK){
    if (k0 + BK < k_end){
      STAGE(cur ^ 1, k0 + BK);
      if constexpr (NS == 8)      asm volatile("s_waitcnt vmcnt(8)" ::: "memory");
      else if constexpr (NS == 6) asm volatile("s_waitcnt vmcnt(6)" ::: "memory");
      else                        asm volatile("s_waitcnt vmcnt(0)" ::: "memory");
    } else {
      asm volatile("s_waitcnt vmcnt(0)" ::: "memory");
    }
    __builtin_amdgcn_s_barrier();
    __builtin_amdgcn_sched_barrier(0);
#pragma unroll
    for (int kh = 0; kh < 2; ++kh){
      const int ss = (kh == 0) ? s0 : s1;
      bf16x8 af[MI], bfv[NJ];
#pragma unroll
      for (int i = 0; i < MI; ++i)
        af[i] = *reinterpret_cast<const bf16x8*>(&As[cur][(wm + i * 16 + lrow) * BK + ss]);
#pragma unroll
      for (int j = 0; j < NJ; ++j)
        bfv[j] = *reinterpret_cast<const bf16x8*>(&Bs[cur][(wn + j * 16 + lrow) * BK + ss]);
#pragma unroll
      for (int i = 0; i < MI; ++i)
#pragma unroll
        for (int j = 0; j < NJ; ++j)
          acc[i][j] = __builtin_amdgcn_mfma_f32_16x16x32_bf16(af[i], bfv[j], acc[i][j], 0, 0, 0);
    }
    __builtin_amdgcn_s_barrier();
    cur ^= 1;
  }

  float csum[NJ];
#pragma unroll
  for (int j = 0; j < NJ; ++j) csum[j] = 0.f;

#pragma unroll
  for (int i = 0; i < MI; ++i){
#pragma unroll
    for (int j = 0; j < NJ; ++j){
      int col = n0 + wn + j * 16 + lrow;
      float bv = (OM < 4 && bias) ? bias[col] : 0.f;
#pragma unroll
      for (int r = 0; r < 4; ++r){
        int row = m0 + wm + i * 16 + lg * 4 + r;
        float x = acc[i][j][r] + bv;
        if (OM == 1){
          if (col < 2048){ x = fast_sigmoid(x); csum[j] += x; }
          int which = col >> 10, cc = col & 1023, h = cc >> 6, d = cc & 63;
          int b = row >> 10, l = row & 1023;
          outB[(size_t)which * (2048ull * 1024) +
               (((size_t)(b * 16 + h)) * 1024 + l) * 64 + d] = f2bf(x);
        } else if (OM == 4){
          outF[((size_t)blockIdx.z * M + row) * N + col] = x;
        } else if (OM == 5){
          outB[((size_t)blockIdx.z * M + row) * N + col] = f2bf(x);
        } else {
          if (ACT == 2){
            float u = 0.7978845608f * (x + 0.044715f * x * x * x);
            float e = __expf(2.f * u);
            x = 0.5f * x * (2.f - 2.f / (e + 1.f));
          }
          outB[(size_t)row * N + col] = f2bf(x);
        }
      }
    }
  }
  // fused chunk-sums: 16 rows per thread (fixed chunk), one atomic per j-frag
  if (OM == 1){
#pragma unroll
    for (int j = 0; j < NJ; ++j){
      int col = n0 + wn + j * 16 + lrow;
      if (col < 2048){
        int which = col >> 10, cc = col & 1023, h = cc >> 6, d = cc & 63;
        int rowbase = m0 + wm;
        int bh = (rowbase >> 10) * 16 + h;
        int chunk = (rowbase & 1023) >> 6;
        float* dst = (which == 0) ? cqA : ckA;
        atomicAdd(&dst[((size_t)bh * 16 + chunk) * 64 + d], csum[j]);
      }
    }
  }
}

// ---------------- attention scalar pipeline (chunked Gram-tile form, bf16 in) ----
__global__ __launch_bounds__(256) void sink_tile(
    const u16* __restrict__ q, const u16* __restrict__ k,
    const float* __restrict__ ck, const float* __restrict__ cq,
    float* __restrict__ sink_in, float* __restrict__ src_out,
    float* __restrict__ cso, float* __restrict__ cqsi)
{
  int blk = blockIdx.x, bh = blk >> 4, c = blk & 15;
  int tid = threadIdx.x, lane = tid & 63, wave = tid >> 6;
  __shared__ float qT[64][65], kT[64][65], G[64][66];
  __shared__ float PK[64], PQ[64];
  __shared__ float rk[64], rq[64], crk[64], crq[64], siv[64], sov[64];
  __shared__ float rd[2][4][64];
  size_t base = ((size_t)bh * LSEQ + c * 64) * DHD;
  const u16* qb = q + base; const u16* kb = k + base;
  for (int c4 = tid; c4 < 1024; c4 += 256){
    int l = c4 >> 4, d0 = (c4 & 15) * 4;
    ushort4 qv = *reinterpret_cast<const ushort4*>(qb + c4 * 4);
    qT[d0+0][l] = bf2f(qv.x); qT[d0+1][l] = bf2f(qv.y);
    qT[d0+2][l] = bf2f(qv.z); qT[d0+3][l] = bf2f(qv.w);
    ushort4 kv = *reinterpret_cast<const ushort4*>(kb + c4 * 4);
    kT[d0+0][l] = bf2f(kv.x); kT[d0+1][l] = bf2f(kv.y);
    kT[d0+2][l] = bf2f(kv.z); kT[d0+3][l] = bf2f(kv.w);
  }
  if (tid < 64){
    float pk = 0.f, pq = 0.f;
    for (int cc = 0; cc < c; cc++){
      pk += ck[((size_t)bh * 16 + cc) * 64 + tid];
      pq += cq[((size_t)bh * 16 + cc) * 64 + tid];
    }
    PK[tid] = pk; PQ[tid] = pq;
  }
  __syncthreads();
  float sumPK = wred64(PK[lane]);
  float sumPQ = wred64(PQ[lane]);
  {
    int l = lane, g = wave;
    float qrow[64];
#pragma unroll
    for (int d = 0; d < 64; d++) qrow[d] = qT[d][l];
    float p[16] = {};
    for (int d = 0; d < 64; d++){
      float qv = qrow[d];
#pragma unroll
      for (int j4 = 0; j4 < 4; j4++){
        float4 kk = *reinterpret_cast<const float4*>(&kT[d][g * 16 + j4 * 4]);
        p[j4*4+0] += qv * kk.x; p[j4*4+1] += qv * kk.y;
        p[j4*4+2] += qv * kk.z; p[j4*4+3] += qv * kk.w;
      }
    }
#pragma unroll
    for (int jj = 0; jj < 16; jj++) G[l][g * 16 + jj] = p[jj];
  }
  {
    float pk_ = 0.f, pq_ = 0.f;
#pragma unroll
    for (int d = wave * 16; d < wave * 16 + 16; d++){
      pk_ += kT[d][lane]; pq_ += qT[d][lane];
    }
    rd[0][wave][lane] = pk_; rd[1][wave][lane] = pq_;
  }
  __syncthreads();
  if (tid < 64){
    rk[tid] = rd[0][0][tid] + rd[0][1][tid] + rd[0][2][tid] + rd[0][3][tid];
    rq[tid] = rd[1][0][tid] + rd[1][1][tid] + rd[1][2][tid] + rd[1][3][tid];
  }
  __syncthreads();
  if (wave == 0)      crk[lane] = wscan64(rk[lane], lane);
  else if (wave == 1) crq[lane] = wscan64(rq[lane], lane);
  __syncthreads();
  {
    int l = lane;
    float p1 = 0.f, p2 = 0.f;
#pragma unroll
    for (int j = wave * 16; j < wave * 16 + 16; j++){
      float g1 = (j <= l) ? G[l][j] : 0.f;
      p1 += g1 + qT[j][l] * PK[j];
      float g2 = (j <= l) ? G[j][l] : 0.f;
      p2 += g2 + kT[j][l] * PQ[j];
    }
    rd[0][wave][l] = p1; rd[1][wave][l] = p2;
  }
  __syncthreads();
  const float EPS2 = 64.f * EPS * EPS;
  if (tid < 64){
    int l = tid;
    float s1 = rd[0][0][l] + rd[0][1][l] + rd[0][2][l] + rd[0][3][l];
    float s2 = rd[1][0][l] + rd[1][1][l] + rd[1][2][l] + rd[1][3][l];
    int L = c * 64 + l; float nrm = (float)(L + 1);
    float den1 = s1 + EPS * rq[l] + EPS * (sumPK + crk[l]) + EPS2;
    float den2 = s2 + EPS * rk[l] + EPS * (sumPQ + crq[l]) + EPS2;
    float si_ = nrm / den1, so_ = nrm / den2;
    sink_in[(size_t)bh * LSEQ + L] = si_;
    src_out[(size_t)bh * LSEQ + L] = so_;
    siv[l] = si_; sov[l] = so_;
  }
  __syncthreads();
  float s1 = 0.f, s2 = 0.f;
  for (int l = wave * 16; l < wave * 16 + 16; l++){
    s1 += sov[l] * kT[lane][l];
    s2 += siv[l] * qT[lane][l];
  }
  rd[0][wave][lane] = s1; rd[1][wave][lane] = s2;
  __syncthreads();
  if (wave == 0){
    cso [(size_t)blk * 64 + lane] = rd[0][0][lane] + rd[0][1][lane] + rd[0][2][lane] + rd[0][3][lane];
    cqsi[(size_t)blk * 64 + lane] = rd[1][0][lane] + rd[1][1][lane] + rd[1][2][lane] + rd[1][3][lane];
  }
}

__global__ __launch_bounds__(256) void cons_tile(
    const u16* __restrict__ q, const u16* __restrict__ k,
    const float* __restrict__ cso, const float* __restrict__ cqsi,
    const float* __restrict__ sink_in, const float* __restrict__ src_out,
    float* __restrict__ sa, float* __restrict__ ebuf)
{
  int blk = blockIdx.x, bh = blk >> 4, c = blk & 15;
  int tid = threadIdx.x, lane = tid & 63, wave = tid >> 6;
  __shared__ float qT[64][65], kT[64][65], G[64][66];
  __shared__ float PKso[64], PQsi[64];
  __shared__ float rk[64], rq[64], cwrk[64], cwrq[64], siv[64], sov[64];
  __shared__ float rd[2][4][64];
  size_t base = ((size_t)bh * LSEQ + c * 64) * DHD;
  const u16* qb = q + base; const u16* kb = k + base;
  for (int c4 = tid; c4 < 1024; c4 += 256){
    int l = c4 >> 4, d0 = (c4 & 15) * 4;
    ushort4 qv = *reinterpret_cast<const ushort4*>(qb + c4 * 4);
    qT[d0+0][l] = bf2f(qv.x); qT[d0+1][l] = bf2f(qv.y);
    qT[d0+2][l] = bf2f(qv.z); qT[d0+3][l] = bf2f(qv.w);
    ushort4 kv = *reinterpret_cast<const ushort4*>(kb + c4 * 4);
    kT[d0+0][l] = bf2f(kv.x); kT[d0+1][l] = bf2f(kv.y);
    kT[d0+2][l] = bf2f(kv.z); kT[d0+3][l] = bf2f(kv.w);
  }
  if (tid < 64){
    float pk = 0.f, pq = 0.f;
    for (int cc = 0; cc < c; cc++){
      pk += cso [((size_t)bh * 16 + cc) * 64 + tid];
      pq += cqsi[((size_t)bh * 16 + cc) * 64 + tid];
    }
    PKso[tid] = pk; PQsi[tid] = pq;
  } else if (tid < 128){
    int l = tid - 64;
    sov[l] = src_out[(size_t)bh * LSEQ + c * 64 + l];
    siv[l] = sink_in[(size_t)bh * LSEQ + c * 64 + l];
  }
  __syncthreads();
  float sumPKso = wred64(PKso[lane]);
  float sumPQsi = wred64(PQsi[lane]);
  {
    int l = lane, g = wave;
    float qrow[64];
#pragma unroll
    for (int d = 0; d < 64; d++) qrow[d] = qT[d][l];
    float p[16] = {};
    for (int d = 0; d < 64; d++){
      float qv = qrow[d];
#pragma unroll
      for (int j4 = 0; j4 < 4; j4++){
        float4 kk = *reinterpret_cast<const float4*>(&kT[d][g * 16 + j4 * 4]);
        p[j4*4+0] += qv * kk.x; p[j4*4+1] += qv * kk.y;
        p[j4*4+2] += qv * kk.z; p[j4*4+3] += qv * kk.w;
      }
    }
#pragma unroll
    for (int jj = 0; jj < 16; jj++) G[l][g * 16 + jj] = p[jj];
  }
  {
    float pk_ = 0.f, pq_ = 0.f;
#pragma unroll
    for (int d = wave * 16; d < wave * 16 + 16; d++){
      pk_ += kT[d][lane]; pq_ += qT[d][lane];
    }
    rd[0][wave][lane] = pk_; rd[1][wave][lane] = pq_;
  }
  __syncthreads();
  if (tid < 64){
    rk[tid] = rd[0][0][tid] + rd[0][1][tid] + rd[0][2][tid] + rd[0][3][tid];
    rq[tid] = rd[1][0][tid] + rd[1][1][tid] + rd[1][2][tid] + rd[1][3][tid];
  }
  __syncthreads();
  if (wave == 0)      cwrk[lane] = wscan64(sov[lane] * rk[lane], lane);
  else if (wave == 1) cwrq[lane] = wscan64(siv[lane] * rq[lane], lane);
  __syncthreads();
  {
    int l = lane;
    float p3 = 0.f, p4 = 0.f;
#pragma unroll
    for (int j = wave * 16; j < wave * 16 + 16; j++){
      float g3 = (j <= l) ? sov[j] * G[l][j] : 0.f;
      p3 += g3 + qT[j][l] * PKso[j];
      float g4 = (j <= l) ? siv[j] * G[j][l] : 0.f;
      p4 += g4 + kT[j][l] * PQsi[j];
    }
    rd[0][wave][l] = p3; rd[1][wave][l] = p4;
  }
  __syncthreads();
  const float EPS2 = 64.f * EPS * EPS;
  if (tid < 64){
    int l = tid;
    float s3 = rd[0][0][l] + rd[0][1][l] + rd[0][2][l] + rd[0][3][l];
    float s4 = rd[1][0][l] + rd[1][1][l] + rd[1][2][l] + rd[1][3][l];
    int L = c * 64 + l; float nrm = (float)(L + 1);
    float cs = (s3 + EPS * rq[l] + EPS * (sumPKso + cwrk[l]) + EPS2) / nrm;
    sa[(size_t)bh * LSEQ + L] = fast_sigmoid(cs);
    float c2 = (s4 + EPS * rk[l] + EPS * (sumPQsi + cwrq[l]) + EPS2) / nrm;
    c2 = fminf(1.f, fmaxf(-1.f, c2));
    ebuf[(size_t)bh * LSEQ + L] = __expf(c2);
  }
}

// ---------------- chunked causal linear attention (inline sc, bf16 S) ------
// sc[L] = e[L]/cumsum(e)[L]*(L+1), computed per block by wave 0 (replaces srccomp)
__global__ __launch_bounds__(256) void phaseA(const u16* __restrict__ k, const u16* __restrict__ v,
                                              const float* __restrict__ ebuf, u16* __restrict__ S){
  int blk = blockIdx.x; int bh = blk >> 4, c = blk & 15;
  if (c == 15) return;                 // chunk 15's S is never read
  __shared__ float ks[64][68], vss[64][68];
  __shared__ float vc[64];
  int tid = threadIdx.x, lane = tid & 63, wave = tid >> 6;
  size_t base = ((size_t)bh * LSEQ + c * 64) * DHD;
  const u16* kb = k + base; const u16* vb = v + base;
  // preload raw k/v into registers (overlaps with sc computation)
  ushort4 kr[4], vr[4];
#pragma unroll
  for (int it = 0; it < 4; it++){
    int c4 = tid + it * 256;
    kr[it] = *reinterpret_cast<const ushort4*>(kb + c4 * 4);
    vr[it] = *reinterpret_cast<const ushort4*>(vb + c4 * 4);
  }
  if (wave == 0){
    const float* eb = ebuf + (size_t)bh * LSEQ;
    float basep = 0.f;
    for (int cc = 0; cc < c; cc++) basep += eb[cc * 64 + lane];
    float bsum = wred64(basep);                 // sum e over [0, c*64)
    float ev = eb[c * 64 + lane];
    float cums = bsum + wscan64(ev, lane);      // inclusive cumsum at row L
    vc[lane] = ev / cums * (float)(c * 64 + lane + 1);
  }
  __syncthreads();
#pragma unroll
  for (int it = 0; it < 4; it++){
    int c4 = tid + it * 256;
    int l = c4 >> 4, d0 = (c4 & 15) * 4;
    ks[l][d0+0] = bf2f(kr[it].x); ks[l][d0+1] = bf2f(kr[it].y);
    ks[l][d0+2] = bf2f(kr[it].z); ks[l][d0+3] = bf2f(kr[it].w);
    float w = vc[l];
    vss[l][d0+0] = bf2f(vr[it].x) * w; vss[l][d0+1] = bf2f(vr[it].y) * w;
    vss[l][d0+2] = bf2f(vr[it].z) * w; vss[l][d0+3] = bf2f(vr[it].w) * w;
  }
  __syncthreads();
  int m = tid >> 2, dg = tid & 3;
  float acc[16] = {};
  for (int l = 0; l < 64; l++){
    float vm = vss[l][m];
#pragma unroll
    for (int d4 = 0; d4 < 4; d4++){
      float4 kk = *reinterpret_cast<const float4*>(&ks[l][dg * 16 + d4 * 4]);
      acc[d4*4+0] += vm * kk.x; acc[d4*4+1] += vm * kk.y;
      acc[d4*4+2] += vm * kk.z; acc[d4*4+3] += vm * kk.w;
    }
  }
  u16* Sb = S + (size_t)blk * 4096 + m * 64 + dg * 16;
#pragma unroll
  for (int d4 = 0; d4 < 4; d4++){
    ushort4 o;
    o.x = f2bf(acc[d4*4+0]); o.y = f2bf(acc[d4*4+1]);
    o.z = f2bf(acc[d4*4+2]); o.w = f2bf(acc[d4*4+3]);
    *reinterpret_cast<ushort4*>(Sb + d4 * 4) = o;
  }
}

// phase C with inlined KV-prefix (bf16 S, 16B loads), inline sc, reg-preloaded
// staging; Ps overlays qsT (qrow registers cached first)
__global__ __launch_bounds__(256) void phaseC(const u16* __restrict__ q, const u16* __restrict__ k,
                                              const u16* __restrict__ v, const u16* __restrict__ S,
                                              const float* __restrict__ sink_in, const float* __restrict__ ebuf,
                                              const float* __restrict__ sa, u16* __restrict__ x){
  int blk = blockIdx.x; int bh = blk >> 4, c = blk & 15;
  int b = bh >> 4, h = bh & 15;
  __shared__ float qp[64][66];      // qsT[d][l] first, then Ps[l][j]
  __shared__ float kT[64][68];
  __shared__ float vss[64][68];
  __shared__ float kvs[64][68];
  __shared__ float qc[64], vc[64];
  int tid = threadIdx.x, lane = tid & 63, wave = tid >> 6;
  size_t base = ((size_t)bh * LSEQ + c * 64) * DHD;
  const u16* qb = q + base; const u16* kb = k + base; const u16* vb = v + base;
  // preload raw q/k/v into registers (overlaps with KV-prefix chain below)
  ushort4 qr[4], kr[4], vr[4];
#pragma unroll
  for (int it = 0; it < 4; it++){
    int c4 = tid + it * 256;
    qr[it] = *reinterpret_cast<const ushort4*>(qb + c4 * 4);
    kr[it] = *reinterpret_cast<const ushort4*>(kb + c4 * 4);
    vr[it] = *reinterpret_cast<const ushort4*>(vb + c4 * 4);
  }
  if (wave == 0){
    int L = c * 64 + lane;
    qc[lane] = sink_in[(size_t)bh * LSEQ + L] / (float)(L + 1);
    const float* eb = ebuf + (size_t)bh * LSEQ;
    float basep = 0.f;
    for (int cc = 0; cc < c; cc++) basep += eb[cc * 64 + lane];
    float bsum = wred64(basep);
    float ev = eb[c * 64 + lane];
    float cums = bsum + wscan64(ev, lane);
    vc[lane] = ev / cums * (float)(L + 1);
  }
  // KV prefix: accumulate 16 bf16 elements per thread over chunks 0..c-1 (16B loads)
  {
    int off16 = tid * 16;
    float accp[16] = {};
    for (int cc = 0; cc < c; cc++){
      size_t idx = ((size_t)bh * 16 + cc) * 4096 + off16;
      const uint4* sp = reinterpret_cast<const uint4*>(S + idx);
      uint4 w0 = sp[0], w1 = sp[1];
      acc8(&accp[0], w0);
      acc8(&accp[8], w1);
    }
#pragma unroll
    for (int e = 0; e < 16; e++){
      int j = off16 + e;
      kvs[j >> 6][j & 63] = accp[e];
    }
  }
  __syncthreads();
#pragma unroll
  for (int it = 0; it < 4; it++){
    int c4 = tid + it * 256;
    int l = c4 >> 4, d0 = (c4 & 15) * 4;
    float qw = qc[l], vw = vc[l];
    qp[d0+0][l] = bf2f(qr[it].x) * qw; qp[d0+1][l] = bf2f(qr[it].y) * qw;
    qp[d0+2][l] = bf2f(qr[it].z) * qw; qp[d0+3][l] = bf2f(qr[it].w) * qw;
    kT[d0+0][l] = bf2f(kr[it].x); kT[d0+1][l] = bf2f(kr[it].y);
    kT[d0+2][l] = bf2f(kr[it].z); kT[d0+3][l] = bf2f(kr[it].w);
    vss[l][d0+0] = bf2f(vr[it].x) * vw; vss[l][d0+1] = bf2f(vr[it].y) * vw;
    vss[l][d0+2] = bf2f(vr[it].z) * vw; vss[l][d0+3] = bf2f(vr[it].w) * vw;
  }
  __syncthreads();
  int l = tid & 63, g = tid >> 6;
  float qrow[64];
#pragma unroll
  for (int d = 0; d < 64; d++) qrow[d] = qp[d][l];
  __syncthreads();

  float p[16] = {};
  for (int d = 0; d < 64; d++){
    float qv = qrow[d];
#pragma unroll
    for (int j4 = 0; j4 < 4; j4++){
      float4 kk = *reinterpret_cast<const float4*>(&kT[d][g * 16 + j4 * 4]);
      p[j4*4+0] += qv * kk.x; p[j4*4+1] += qv * kk.y;
      p[j4*4+2] += qv * kk.z; p[j4*4+3] += qv * kk.w;
    }
  }
#pragma unroll
  for (int jj = 0; jj < 16; jj++){
    int j = g * 16 + jj;
    qp[l][j] = (j <= l) ? p[jj] : 0.f;
  }
  __syncthreads();

  float acc[16];
#pragma unroll
  for (int mm = 0; mm < 16; mm++){
    float a = 0.f;
#pragma unroll
    for (int d4 = 0; d4 < 16; d4++){
      float4 kv4 = *reinterpret_cast<const float4*>(&kvs[g * 16 + mm][d4 * 4]);
      a += qrow[d4*4+0]*kv4.x + qrow[d4*4+1]*kv4.y + qrow[d4*4+2]*kv4.z + qrow[d4*4+3]*kv4.w;
    }
    acc[mm] = a;
  }
  for (int j = 0; j < 64; j++){
    float pv = qp[l][j];
#pragma unroll
    for (int m4 = 0; m4 < 4; m4++){
      float4 vv = *reinterpret_cast<const float4*>(&vss[j][g * 16 + m4 * 4]);
      acc[m4*4+0] += pv * vv.x; acc[m4*4+1] += pv * vv.y;
      acc[m4*4+2] += pv * vv.z; acc[m4*4+3] += pv * vv.w;
    }
  }
  float sav = sa[(size_t)bh * LSEQ + c * 64 + l];
  u16* xo = x + ((size_t)(b * 1024 + c * 64 + l)) * 1024 + h * 64 + g * 16;
#pragma unroll
  for (int mm = 0; mm < 16; mm++) xo[mm] = f2bf(acc[mm] * sav);
}

// ---------------- fused layernorms ----------------
// LN over (bf16 p0+p1 + bias + resid); emits f32 + bf16 (Wo split-K + LN1)
__global__ __launch_bounds__(256) void ln_fused2b(
    const u16* __restrict__ p0, const u16* __restrict__ p1,
    const float* __restrict__ resid, const float* __restrict__ bias,
    const float* __restrict__ g, const float* __restrict__ b,
    float* __restrict__ out, u16* __restrict__ outbf){
  int row = blockIdx.x; int tid = threadIdx.x;
  int lane = tid & 63, wave = tid >> 6;
  size_t off = (size_t)row * 1024 + tid * 4;
  ushort4 a0 = *reinterpret_cast<const ushort4*>(p0 + off);
  ushort4 a1 = *reinterpret_cast<const ushort4*>(p1 + off);
  float4 rr = *reinterpret_cast<const float4*>(resid + off);
  float4 bb = *reinterpret_cast<const float4*>(bias + tid * 4);
  float4 v = make_float4(bf2f(a0.x) + bf2f(a1.x) + rr.x + bb.x,
                         bf2f(a0.y) + bf2f(a1.y) + rr.y + bb.y,
                         bf2f(a0.z) + bf2f(a1.z) + rr.z + bb.z,
                         bf2f(a0.w) + bf2f(a1.w) + rr.w + bb.w);
  float s = v.x + v.y + v.z + v.w;
  float s2 = v.x*v.x + v.y*v.y + v.z*v.z + v.w*v.w;
  s = wred64(s); s2 = wred64(s2);
  __shared__ float red[2][4];
  if (lane == 0){ red[0][wave] = s; red[1][wave] = s2; }
  __syncthreads();
  float S = red[0][0] + red[0][1] + red[0][2] + red[0][3];
  float S2 = red[1][0] + red[1][1] + red[1][2] + red[1][3];
  float mean = S * (1.f / 1024.f);
  float var = S2 * (1.f / 1024.f) - mean * mean;
  float inv = rsqrtf(var + 1e-5f);
  float4 gv = *reinterpret_cast<const float4*>(g + tid * 4);
  float4 bv = *reinterpret_cast<const float4*>(b + tid * 4);
  float y0 = (v.x - mean) * inv * gv.x + bv.x;
  float y1 = (v.y - mean) * inv * gv.y + bv.y;
  float y2 = (v.z - mean) * inv * gv.z + bv.z;
  float y3 = (v.w - mean) * inv * gv.w + bv.w;
  *reinterpret_cast<float4*>(out + off) = make_float4(y0, y1, y2, y3);
  ushort4 o; o.x = f2bf(y0); o.y = f2bf(y1); o.z = f2bf(y2); o.w = f2bf(y3);
  *reinterpret_cast<ushort4*>(outbf + off) = o;
}

// LN over (bf16 p0..p3 + bias + resid) -> f32 out (FFN2 split-K4 combine + LN2)
__global__ __launch_bounds__(256) void ln_fused4b(
    const u16* __restrict__ p0, const u16* __restrict__ p1,
    const u16* __restrict__ p2, const u16* __restrict__ p3,
    const float* __restrict__ resid, const float* __restrict__ bias,
    const float* __restrict__ g, const float* __restrict__ b,
    float* __restrict__ out){
  int row = blockIdx.x; int tid = threadIdx.x;
  int lane = tid & 63, wave = tid >> 6;
  size_t off = (size_t)row * 1024 + tid * 4;
  ushort4 u0 = *reinterpret_cast<const ushort4*>(p0 + off);
  ushort4 u1 = *reinterpret_cast<const ushort4*>(p1 + off);
  ushort4 u2 = *reinterpret_cast<const ushort4*>(p2 + off);
  ushort4 u3 = *reinterpret_cast<const ushort4*>(p3 + off);
  float4 rr = *reinterpret_cast<const float4*>(resid + off);
  float4 bb = *reinterpret_cast<const float4*>(bias + tid * 4);
  float4 v = make_float4(
      bf2f(u0.x) + bf2f(u1.x) + bf2f(u2.x) + bf2f(u3.x) + rr.x + bb.x,
      bf2f(u0.y) + bf2f(u1.y) + bf2f(u2.y) + bf2f(u3.y) + rr.y + bb.y,
      bf2f(u0.z) + bf2f(u1.z) + bf2f(u2.z) + bf2f(u3.z) + rr.z + bb.z,
      bf2f(u0.w) + bf2f(u1.w) + bf2f(u2.w) + bf2f(u3.w) + rr.w + bb.w);
  float s = v.x + v.y + v.z + v.w;
  float s2 = v.x*v.x + v.y*v.y + v.z*v.z + v.w*v.w;
  s = wred64(s); s2 = wred64(s2);
  __shared__ float red[2][4];
  if (lane == 0){ red[0][wave] = s; red[1][wave] = s2; }
  __syncthreads();
  float S = red[0][0] + red[0][1] + red[0][2] + red[0][3];
  float S2 = red[1][0] + red[1][1] + red[1][2] + red[1][3];
  float mean = S * (1.f / 1024.f);
  float var = S2 * (1.f / 1024.f) - mean * mean;
  float inv = rsqrtf(var + 1e-5f);
  float4 gv = *reinterpret_cast<const float4*>(g + tid * 4);
  float4 bv = *reinterpret_cast<const float4*>(b + tid * 4);
  float y0 = (v.x - mean) * inv * gv.x + bv.x;
  float y1 = (v.y - mean) * inv * gv.y + bv.y;
  float y2 = (v.z - mean) * inv * gv.z + bv.z;
  float y3 = (v.w - mean) * inv * gv.w + bv.w;
  *reinterpret_cast<float4*>(out + off) = make_float4(y0, y1, y2, y3);
}

// ---------------- launch ----------------
extern "C" void kernel_launch(void* const* d_in, const int* in_sizes, int n_in,
                              void* d_out, int out_size, void* d_ws, size_t ws_size,
                              hipStream_t stream){
  (void)in_sizes; (void)n_in; (void)out_size; (void)ws_size;
  const float* inputs = (const float*)d_in[0];
  const float* Wq = (const float*)d_in[2];  const float* bq = (const float*)d_in[3];
  const float* Wk = (const float*)d_in[4];  const float* bk = (const float*)d_in[5];
  const float* Wv = (const float*)d_in[6];  const float* bv = (const float*)d_in[7];
  const float* Wo = (const float*)d_in[8];  const float* bo = (const float*)d_in[9];
  const float* ln1g = (const float*)d_in[10]; const float* ln1b = (const float*)d_in[11];
  const float* W1 = (const float*)d_in[12]; const float* b1 = (const float*)d_in[13];
  const float* W2 = (const float*)d_in[14]; const float* b2 = (const float*)d_in[15];
  const float* ln2g = (const float*)d_in[16]; const float* ln2b = (const float*)d_in[17];
  float* out = (float*)d_out;

  char* wsp = (char*)d_ws; size_t off = 0;
  auto alloc = [&](size_t bytes) -> void* {
    off = (off + 255) & ~(size_t)255;
    void* p = wsp + off; off += bytes; return p;
  };
  const size_t MD = (size_t)2048 * 1024;
  u16* Xbf    = (u16*)alloc(MD * 2);
  u16* WqkvT  = (u16*)alloc((size_t)3 * 1024 * 1024 * 2);
  u16* WoT    = (u16*)alloc((size_t)1024 * 1024 * 2);
  u16* W1T    = (u16*)alloc((size_t)4096 * 1024 * 2);
  u16* W2T    = (u16*)alloc((size_t)4096 * 1024 * 2);
  float* bqkv = (float*)alloc(3072 * 4);
  u16* qkvb   = (u16*)alloc(3 * MD * 2);     // bf16 q|k|v in [B,H,L,DH]
  u16* qb = qkvb; u16* kb = qkvb + MD; u16* vb = qkvb + 2 * MD;
  float* quad = (float*)alloc(4 * MD * 4);
  u16* Sbuf   = (u16*)quad;                  // bf16 S: 512 x 4096 x 2B = 4MB
  float* ckb  = (float*)alloc((size_t)512 * 64 * 4);   // contiguous with cqb
  float* cqb  = (float*)alloc((size_t)512 * 64 * 4);
  float* csob = (float*)alloc((size_t)512 * 64 * 4);
  float* cqsib= (float*)alloc((size_t)512 * 64 * 4);
  float* sink_in = (float*)alloc(NBH * LSEQ * 4);
  float* src_out = (float*)alloc(NBH * LSEQ * 4);
  float* sabuf   = (float*)alloc(NBH * LSEQ * 4);
  float* ebuf    = (float*)alloc(NBH * LSEQ * 4);
  u16* xatt   = (u16*)alloc(MD * 2);
  u16* g1     = (u16*)alloc((size_t)2048 * 4096 * 2);
  // quad reuse: slot0 Sbuf(bf16,4MB) -> hbuf (f32 LN1 out, 8MB); slot1 hbf (bf16);
  // slots2-3: Wo bf16 partials (8MB) then FFN2 bf16 partials (16MB)
  float* hbuf  = quad;
  u16* hbf     = (u16*)(quad + MD);
  u16* wopart  = (u16*)(quad + 2 * MD);
  u16* partb   = (u16*)(quad + 2 * MD);

  // all prep in one launch (+64 blocks zeroing ckb||cqb)
  prep_all<<<14412, 256, 0, stream>>>(inputs, Xbf, Wq, Wk, Wv, Wo, WqkvT, WoT,
                                      W1, W2, W1T, W2T, bq, bk, bv, bqkv, ckb);

  // fused QKV projection (bf16 out) + chunk-sum atomics: BM=128,BN=64, grid 16x48
  gemm_mfma<128, 64, 0, 1><<<dim3(16, 48), 256, 0, stream>>>(
      Xbf, WqkvT, bqkv, nullptr, nullptr, qkvb, cqb, ckb, 2048, 3072, 1024);

  // attention scalars (chunked Gram-tile pipeline, bf16 inputs)
  sink_tile<<<512, 256, 0, stream>>>(qb, kb, ckb, cqb, sink_in, src_out, csob, cqsib);
  cons_tile<<<512, 256, 0, stream>>>(qb, kb, csob, cqsib, sink_in, src_out, sabuf, ebuf);

  // chunked causal linear attention (inline sc; bf16 S; KV-prefix in phaseC)
  phaseA<<<512, 256, 0, stream>>>(kb, vb, ebuf, Sbuf);
  phaseC<<<512, 256, 0, stream>>>(qb, kb, vb, Sbuf, sink_in, ebuf, sabuf, xatt);

  // output projection: BM=128,BN=64, split-K=2, bf16 partials
  gemm_mfma<128, 64, 0, 5><<<dim3(16, 16, 2), 256, 0, stream>>>(
      xatt, WoT, nullptr, nullptr, nullptr, wopart, nullptr, nullptr, 2048, 1024, 1024);
  ln_fused2b<<<2048, 256, 0, stream>>>(wopart, wopart + MD, inputs, bo, ln1g, ln1b, hbuf, hbf);

  // FFN1: BM=128,BN=128 (fast gelu)
  gemm_mfma<128, 128, 2, 3><<<dim3(16, 32), 256, 0, stream>>>(
      hbf, W1T, b1, nullptr, nullptr, g1, nullptr, nullptr, 2048, 4096, 1024);
  // FFN2: BM=128,BN=128, split-K=4, bf16 partials
  gemm_mfma<128, 128, 0, 5><<<dim3(16, 8, 4), 256, 0, stream>>>(
      g1, W2T, nullptr, nullptr, nullptr, partb, nullptr, nullptr, 2048, 1024, 4096);
  ln_fused4b<<<2048, 256, 0, stream>>>(partb, partb + MD, partb + 2 * MD, partb + 3 * MD,
                                       hbuf, b2, ln2g, ln2b, out);
}

// Round 19
// 188.035 us; speedup vs baseline: 1.0251x; 1.0251x over previous
//
#include <hip/hip_runtime.h>
#include <hip/hip_bf16.h>

// ---------------- constants ----------------
#define EPS 1e-6f
#define NBH 32      // B*H
#define LSEQ 1024
#define DHD 64

typedef unsigned short u16;
typedef __bf16 bf16x8 __attribute__((ext_vector_type(8)));
typedef float f32x4 __attribute__((ext_vector_type(4)));

__device__ inline u16 f2bf(float f){
  union { float f; unsigned u; } un; un.f = f;
  unsigned u = un.u;
  u += 0x7fffu + ((u >> 16) & 1u);
  return (u16)(u >> 16);
}

__device__ inline float bf2f(u16 v){
  union { unsigned u; float f; } un; un.u = ((unsigned)v) << 16; return un.f;
}

__device__ inline float wred64(float v){
#pragma unroll
  for (int off = 32; off > 0; off >>= 1) v += __shfl_xor(v, off, 64);
  return v;
}

__device__ inline float wscan64(float v, int lane){
  float run = v;
#pragma unroll
  for (int off = 1; off < 64; off <<= 1){
    float t = __shfl_up(run, off, 64);
    if (lane >= off) run += t;
  }
  return run;   // inclusive
}

__device__ inline float fast_sigmoid(float x){
  return 1.f / (1.f + __expf(-x));
}

__device__ inline void gload_lds16(const u16* g, u16* l){
  __builtin_amdgcn_global_load_lds(
      (const __attribute__((address_space(1))) unsigned int*)g,
      (__attribute__((address_space(3))) unsigned int*)l, 16, 0, 0);
}

// ---------------- mega prep kernel (f2bf + 6 transposes + bias + zero) -------
__device__ inline void tr_tile2(const float* in, u16* out, int R, int C, int r0, int c0){
  __shared__ float tile[32][33];
  int x = threadIdx.x & 31, y = threadIdx.x >> 5;
#pragma unroll
  for (int j = 0; j < 4; j++)
    tile[y + j*8][x] = in[(size_t)(r0 + y + j*8) * C + c0 + x];
  __syncthreads();
#pragma unroll
  for (int j = 0; j < 4; j++)
    out[(size_t)(c0 + y + j*8) * R + r0 + x] = f2bf(tile[x][y + j*8]);
}

// blocks: [0,2048) f2bf inputs; [2048,6144) Wq/Wk/Wv/Wo transposes;
// [6144,14336) W1/W2 transposes; [14336,14348) bias gather;
// [14348,14412) zero ckb||cqb (contiguous 256KB)
__global__ __launch_bounds__(256) void prep_all(
    const float* __restrict__ inputs, u16* __restrict__ Xbf,
    const float* __restrict__ Wq, const float* __restrict__ Wk,
    const float* __restrict__ Wv, const float* __restrict__ Wo,
    u16* __restrict__ dqkv, u16* __restrict__ dwo,
    const float* __restrict__ W1, const float* __restrict__ W2,
    u16* __restrict__ d1, u16* __restrict__ d2,
    const float* __restrict__ bq, const float* __restrict__ bk,
    const float* __restrict__ bv, float* __restrict__ bqkv,
    float* __restrict__ ckq_zero)
{
  int b = blockIdx.x;
  if (b < 2048){
    int i = b * 256 + threadIdx.x;
    float4 v = reinterpret_cast<const float4*>(inputs)[i];
    ushort4 o; o.x = f2bf(v.x); o.y = f2bf(v.y); o.z = f2bf(v.z); o.w = f2bf(v.w);
    reinterpret_cast<ushort4*>(Xbf)[i] = o;
  } else if (b < 6144){
    int t = b - 2048;
    int z = t >> 10, rem = t & 1023;
    int bx = rem & 31, by = rem >> 5;
    const float* in = (z == 0) ? Wq : (z == 1) ? Wk : (z == 2) ? Wv : Wo;
    u16* out = (z < 3) ? (dqkv + (size_t)z * 1024 * 1024) : dwo;
    tr_tile2(in, out, 1024, 1024, by * 32, bx * 32);
  } else if (b < 14336){
    int t = b - 6144;
    int z = t >> 12, rem = t & 4095;
    int bx = rem & 127, by = rem >> 7;
    if (z == 0) tr_tile2(W1, d1, 1024, 4096, by * 32, bx * 32);
    else        tr_tile2(W2, d2, 4096, 1024, bx * 32, by * 32);
  } else if (b < 14348){
    int i = (b - 14336) * 256 + threadIdx.x;
    if (i < 3072){
      float v = (i < 1024) ? bq[i] : (i < 2048) ? bk[i - 1024] : bv[i - 2048];
      bqkv[i] = v;
    }
  } else {
    int i = (b - 14348) * 256 + threadIdx.x;
    reinterpret_cast<float4*>(ckq_zero)[i] = make_float4(0.f, 0.f, 0.f, 0.f);
  }
}

// ---------------- bf16 MFMA GEMM (dbuf + counted vmcnt, T2 XOR-swizzled LDS) ----
// C[M,N] = act(A[M,K] @ Bt[N,K]^T + bias)
// LDS: BK=64 bf16 rows = 8 x 16B slots; slot s of row r at phys slot s^(r&7)
// (rule #21: linear gload_lds dest + pre-swizzled SOURCE + swizzled READ).
// Pipeline: STAGE(next) before compute(cur); counted vmcnt across the barrier.
// ACT: 0 none, 2 gelu  (OM==1 applies fast sigmoid for col<2048 internally)
// OM: 1 fused-QKV bf16 remap to 3x[B,H,L,DH] + chunk-sum atomics into cq/ck;
//     3 bf16 [M][N]; 4 raw f32 partial (slice z at outF + z*M*N);
//     5 bf16 partial (slice z at outB + z*M*N)
template<int BM, int BN, int ACT, int OM>
__global__ __launch_bounds__(256) void gemm_mfma(
    const u16* __restrict__ A, const u16* __restrict__ Bt,
    const float* __restrict__ bias, const float* __restrict__ resid,
    float* __restrict__ outF, u16* __restrict__ outB,
    float* __restrict__ cqA, float* __restrict__ ckA,
    int M, int N, int K)
{
  constexpr int BK = 64;
  constexpr int MI = BM / 32;
  constexpr int NJ = BN / 32;
  constexpr int RA = BM / 32;
  constexpr int RB = BN / 32;
  constexpr int NS = RA + RB;
  __shared__ u16 As[2][BM * BK];
  __shared__ u16 Bs[2][BN * BK];
  const int tid = threadIdx.x;
  const int lane = tid & 63, wave = tid >> 6;
  const int lrow = lane & 15, lg = lane >> 4;
  const int m0 = blockIdx.x * BM, n0 = blockIdx.y * BN;
  const int wm = (wave >> 1) * (BM / 2), wn = (wave & 1) * (BN / 2);

  const int ksz = K / gridDim.z;
  const int k_begin = blockIdx.z * ksz;
  const int k_end = k_begin + ksz;

  f32x4 acc[MI][NJ];
#pragma unroll
  for (int i = 0; i < MI; i++)
#pragma unroll
    for (int j = 0; j < NJ; j++) acc[i][j] = (f32x4){0.f, 0.f, 0.f, 0.f};

  const u16* Ab = A + (size_t)m0 * K;
  const u16* Bb = Bt + (size_t)n0 * K;

  const int s0 = ((0 * 4 + lg) ^ (lrow & 7)) * 8;
  const int s1 = ((1 * 4 + lg) ^ (lrow & 7)) * 8;

  auto STAGE = [&](int buf, int k0){
#pragma unroll
    for (int r = 0; r < RA; ++r){
      int c = r * 256 + tid;
      int row = c >> 3;
      int kk = ((c ^ row) & 7) << 3;
      gload_lds16(Ab + (size_t)row * K + k0 + kk, &As[buf][(r * 256 + wave * 64) * 8]);
    }
#pragma unroll
    for (int r = 0; r < RB; ++r){
      int c = r * 256 + tid;
      int row = c >> 3;
      int kk = ((c ^ row) & 7) << 3;
      gload_lds16(Bb + (size_t)row * K + k0 + kk, &Bs[buf][(r * 256 + wave * 64) * 8]);
    }
  };

  STAGE(0, k_begin);
  int cur = 0;
  for (int k0 = k_begin; k0 < k_end; k0 += BK){
    if (k0 + BK < k_end){
      STAGE(cur ^ 1, k0 + BK);
      if constexpr (NS == 8)      asm volatile("s_waitcnt vmcnt(8)" ::: "memory");
      else if constexpr (NS == 6) asm volatile("s_waitcnt vmcnt(6)" ::: "memory");
      else                        asm volatile("s_waitcnt vmcnt(0)" ::: "memory");
    } else {
      asm volatile("s_waitcnt vmcnt(0)" ::: "memory");
    }
    __builtin_amdgcn_s_barrier();
    __builtin_amdgcn_sched_barrier(0);
#pragma unroll
    for (int kh = 0; kh < 2; ++kh){
      const int ss = (kh == 0) ? s0 : s1;
      bf16x8 af[MI], bfv[NJ];
#pragma unroll
      for (int i = 0; i < MI; ++i)
        af[i] = *reinterpret_cast<const bf16x8*>(&As[cur][(wm + i * 16 + lrow) * BK + ss]);
#pragma unroll
      for (int j = 0; j < NJ; ++j)
        bfv[j] = *reinterpret_cast<const bf16x8*>(&Bs[cur][(wn + j * 16 + lrow) * BK + ss]);
#pragma unroll
      for (int i = 0; i < MI; ++i)
#pragma unroll
        for (int j = 0; j < NJ; ++j)
          acc[i][j] = __builtin_amdgcn_mfma_f32_16x16x32_bf16(af[i], bfv[j], acc[i][j], 0, 0, 0);
    }
    __builtin_amdgcn_s_barrier();
    cur ^= 1;
  }

  float csum[NJ];
#pragma unroll
  for (int j = 0; j < NJ; ++j) csum[j] = 0.f;

#pragma unroll
  for (int i = 0; i < MI; ++i){
#pragma unroll
    for (int j = 0; j < NJ; ++j){
      int col = n0 + wn + j * 16 + lrow;
      float bv = (OM < 4 && bias) ? bias[col] : 0.f;
#pragma unroll
      for (int r = 0; r < 4; ++r){
        int row = m0 + wm + i * 16 + lg * 4 + r;
        float x = acc[i][j][r] + bv;
        if (OM == 1){
          if (col < 2048){ x = fast_sigmoid(x); csum[j] += x; }
          int which = col >> 10, cc = col & 1023, h = cc >> 6, d = cc & 63;
          int b = row >> 10, l = row & 1023;
          outB[(size_t)which * (2048ull * 1024) +
               (((size_t)(b * 16 + h)) * 1024 + l) * 64 + d] = f2bf(x);
        } else if (OM == 4){
          outF[((size_t)blockIdx.z * M + row) * N + col] = x;
        } else if (OM == 5){
          outB[((size_t)blockIdx.z * M + row) * N + col] = f2bf(x);
        } else {
          if (ACT == 2){
            float u = 0.7978845608f * (x + 0.044715f * x * x * x);
            float e = __expf(2.f * u);
            x = 0.5f * x * (2.f - 2.f / (e + 1.f));
          }
          outB[(size_t)row * N + col] = f2bf(x);
        }
      }
    }
  }
  // fused chunk-sums: 16 rows per thread (fixed chunk), one atomic per j-frag
  if (OM == 1){
#pragma unroll
    for (int j = 0; j < NJ; ++j){
      int col = n0 + wn + j * 16 + lrow;
      if (col < 2048){
        int which = col >> 10, cc = col & 1023, h = cc >> 6, d = cc & 63;
        int rowbase = m0 + wm;
        int bh = (rowbase >> 10) * 16 + h;
        int chunk = (rowbase & 1023) >> 6;
        float* dst = (which == 0) ? cqA : ckA;
        atomicAdd(&dst[((size_t)bh * 16 + chunk) * 64 + d], csum[j]);
      }
    }
  }
}

// ---------------- attention scalar pipeline (chunked Gram-tile form, bf16 in) ----
__global__ __launch_bounds__(256) void sink_tile(
    const u16* __restrict__ q, const u16* __restrict__ k,
    const float* __restrict__ ck, const float* __restrict__ cq,
    float* __restrict__ sink_in, float* __restrict__ src_out,
    float* __restrict__ cso, float* __restrict__ cqsi)
{
  int blk = blockIdx.x, bh = blk >> 4, c = blk & 15;
  int tid = threadIdx.x, lane = tid & 63, wave = tid >> 6;
  __shared__ float qT[64][65], kT[64][65], G[64][66];
  __shared__ float PK[64], PQ[64];
  __shared__ float rk[64], rq[64], crk[64], crq[64], siv[64], sov[64];
  __shared__ float rd[2][4][64];
  size_t base = ((size_t)bh * LSEQ + c * 64) * DHD;
  const u16* qb = q + base; const u16* kb = k + base;
  for (int c4 = tid; c4 < 1024; c4 += 256){
    int l = c4 >> 4, d0 = (c4 & 15) * 4;
    ushort4 qv = *reinterpret_cast<const ushort4*>(qb + c4 * 4);
    qT[d0+0][l] = bf2f(qv.x); qT[d0+1][l] = bf2f(qv.y);
    qT[d0+2][l] = bf2f(qv.z); qT[d0+3][l] = bf2f(qv.w);
    ushort4 kv = *reinterpret_cast<const ushort4*>(kb + c4 * 4);
    kT[d0+0][l] = bf2f(kv.x); kT[d0+1][l] = bf2f(kv.y);
    kT[d0+2][l] = bf2f(kv.z); kT[d0+3][l] = bf2f(kv.w);
  }
  if (tid < 64){
    float pk = 0.f, pq = 0.f;
    for (int cc = 0; cc < c; cc++){
      pk += ck[((size_t)bh * 16 + cc) * 64 + tid];
      pq += cq[((size_t)bh * 16 + cc) * 64 + tid];
    }
    PK[tid] = pk; PQ[tid] = pq;
  }
  __syncthreads();
  float sumPK = wred64(PK[lane]);
  float sumPQ = wred64(PQ[lane]);
  {
    int l = lane, g = wave;
    float qrow[64];
#pragma unroll
    for (int d = 0; d < 64; d++) qrow[d] = qT[d][l];
    float p[16] = {};
    for (int d = 0; d < 64; d++){
      float qv = qrow[d];
#pragma unroll
      for (int j4 = 0; j4 < 4; j4++){
        float4 kk = *reinterpret_cast<const float4*>(&kT[d][g * 16 + j4 * 4]);
        p[j4*4+0] += qv * kk.x; p[j4*4+1] += qv * kk.y;
        p[j4*4+2] += qv * kk.z; p[j4*4+3] += qv * kk.w;
      }
    }
#pragma unroll
    for (int jj = 0; jj < 16; jj++) G[l][g * 16 + jj] = p[jj];
  }
  {
    float pk_ = 0.f, pq_ = 0.f;
#pragma unroll
    for (int d = wave * 16; d < wave * 16 + 16; d++){
      pk_ += kT[d][lane]; pq_ += qT[d][lane];
    }
    rd[0][wave][lane] = pk_; rd[1][wave][lane] = pq_;
  }
  __syncthreads();
  if (tid < 64){
    rk[tid] = rd[0][0][tid] + rd[0][1][tid] + rd[0][2][tid] + rd[0][3][tid];
    rq[tid] = rd[1][0][tid] + rd[1][1][tid] + rd[1][2][tid] + rd[1][3][tid];
  }
  __syncthreads();
  if (wave == 0)      crk[lane] = wscan64(rk[lane], lane);
  else if (wave == 1) crq[lane] = wscan64(rq[lane], lane);
  __syncthreads();
  {
    int l = lane;
    float p1 = 0.f, p2 = 0.f;
#pragma unroll
    for (int j = wave * 16; j < wave * 16 + 16; j++){
      float g1 = (j <= l) ? G[l][j] : 0.f;
      p1 += g1 + qT[j][l] * PK[j];
      float g2 = (j <= l) ? G[j][l] : 0.f;
      p2 += g2 + kT[j][l] * PQ[j];
    }
    rd[0][wave][l] = p1; rd[1][wave][l] = p2;
  }
  __syncthreads();
  const float EPS2 = 64.f * EPS * EPS;
  if (tid < 64){
    int l = tid;
    float s1 = rd[0][0][l] + rd[0][1][l] + rd[0][2][l] + rd[0][3][l];
    float s2 = rd[1][0][l] + rd[1][1][l] + rd[1][2][l] + rd[1][3][l];
    int L = c * 64 + l; float nrm = (float)(L + 1);
    float den1 = s1 + EPS * rq[l] + EPS * (sumPK + crk[l]) + EPS2;
    float den2 = s2 + EPS * rk[l] + EPS * (sumPQ + crq[l]) + EPS2;
    float si_ = nrm / den1, so_ = nrm / den2;
    sink_in[(size_t)bh * LSEQ + L] = si_;
    src_out[(size_t)bh * LSEQ + L] = so_;
    siv[l] = si_; sov[l] = so_;
  }
  __syncthreads();
  float s1 = 0.f, s2 = 0.f;
  for (int l = wave * 16; l < wave * 16 + 16; l++){
    s1 += sov[l] * kT[lane][l];
    s2 += siv[l] * qT[lane][l];
  }
  rd[0][wave][lane] = s1; rd[1][wave][lane] = s2;
  __syncthreads();
  if (wave == 0){
    cso [(size_t)blk * 64 + lane] = rd[0][0][lane] + rd[0][1][lane] + rd[0][2][lane] + rd[0][3][lane];
    cqsi[(size_t)blk * 64 + lane] = rd[1][0][lane] + rd[1][1][lane] + rd[1][2][lane] + rd[1][3][lane];
  }
}

__global__ __launch_bounds__(256) void cons_tile(
    const u16* __restrict__ q, const u16* __restrict__ k,
    const float* __restrict__ cso, const float* __restrict__ cqsi,
    const float* __restrict__ sink_in, const float* __restrict__ src_out,
    float* __restrict__ sa, float* __restrict__ ebuf)
{
  int blk = blockIdx.x, bh = blk >> 4, c = blk & 15;
  int tid = threadIdx.x, lane = tid & 63, wave = tid >> 6;
  __shared__ float qT[64][65], kT[64][65], G[64][66];
  __shared__ float PKso[64], PQsi[64];
  __shared__ float rk[64], rq[64], cwrk[64], cwrq[64], siv[64], sov[64];
  __shared__ float rd[2][4][64];
  size_t base = ((size_t)bh * LSEQ + c * 64) * DHD;
  const u16* qb = q + base; const u16* kb = k + base;
  for (int c4 = tid; c4 < 1024; c4 += 256){
    int l = c4 >> 4, d0 = (c4 & 15) * 4;
    ushort4 qv = *reinterpret_cast<const ushort4*>(qb + c4 * 4);
    qT[d0+0][l] = bf2f(qv.x); qT[d0+1][l] = bf2f(qv.y);
    qT[d0+2][l] = bf2f(qv.z); qT[d0+3][l] = bf2f(qv.w);
    ushort4 kv = *reinterpret_cast<const ushort4*>(kb + c4 * 4);
    kT[d0+0][l] = bf2f(kv.x); kT[d0+1][l] = bf2f(kv.y);
    kT[d0+2][l] = bf2f(kv.z); kT[d0+3][l] = bf2f(kv.w);
  }
  if (tid < 64){
    float pk = 0.f, pq = 0.f;
    for (int cc = 0; cc < c; cc++){
      pk += cso [((size_t)bh * 16 + cc) * 64 + tid];
      pq += cqsi[((size_t)bh * 16 + cc) * 64 + tid];
    }
    PKso[tid] = pk; PQsi[tid] = pq;
  } else if (tid < 128){
    int l = tid - 64;
    sov[l] = src_out[(size_t)bh * LSEQ + c * 64 + l];
    siv[l] = sink_in[(size_t)bh * LSEQ + c * 64 + l];
  }
  __syncthreads();
  float sumPKso = wred64(PKso[lane]);
  float sumPQsi = wred64(PQsi[lane]);
  {
    int l = lane, g = wave;
    float qrow[64];
#pragma unroll
    for (int d = 0; d < 64; d++) qrow[d] = qT[d][l];
    float p[16] = {};
    for (int d = 0; d < 64; d++){
      float qv = qrow[d];
#pragma unroll
      for (int j4 = 0; j4 < 4; j4++){
        float4 kk = *reinterpret_cast<const float4*>(&kT[d][g * 16 + j4 * 4]);
        p[j4*4+0] += qv * kk.x; p[j4*4+1] += qv * kk.y;
        p[j4*4+2] += qv * kk.z; p[j4*4+3] += qv * kk.w;
      }
    }
#pragma unroll
    for (int jj = 0; jj < 16; jj++) G[l][g * 16 + jj] = p[jj];
  }
  {
    float pk_ = 0.f, pq_ = 0.f;
#pragma unroll
    for (int d = wave * 16; d < wave * 16 + 16; d++){
      pk_ += kT[d][lane]; pq_ += qT[d][lane];
    }
    rd[0][wave][lane] = pk_; rd[1][wave][lane] = pq_;
  }
  __syncthreads();
  if (tid < 64){
    rk[tid] = rd[0][0][tid] + rd[0][1][tid] + rd[0][2][tid] + rd[0][3][tid];
    rq[tid] = rd[1][0][tid] + rd[1][1][tid] + rd[1][2][tid] + rd[1][3][tid];
  }
  __syncthreads();
  if (wave == 0)      cwrk[lane] = wscan64(sov[lane] * rk[lane], lane);
  else if (wave == 1) cwrq[lane] = wscan64(siv[lane] * rq[lane], lane);
  __syncthreads();
  {
    int l = lane;
    float p3 = 0.f, p4 = 0.f;
#pragma unroll
    for (int j = wave * 16; j < wave * 16 + 16; j++){
      float g3 = (j <= l) ? sov[j] * G[l][j] : 0.f;
      p3 += g3 + qT[j][l] * PKso[j];
      float g4 = (j <= l) ? siv[j] * G[j][l] : 0.f;
      p4 += g4 + kT[j][l] * PQsi[j];
    }
    rd[0][wave][l] = p3; rd[1][wave][l] = p4;
  }
  __syncthreads();
  const float EPS2 = 64.f * EPS * EPS;
  if (tid < 64){
    int l = tid;
    float s3 = rd[0][0][l] + rd[0][1][l] + rd[0][2][l] + rd[0][3][l];
    float s4 = rd[1][0][l] + rd[1][1][l] + rd[1][2][l] + rd[1][3][l];
    int L = c * 64 + l; float nrm = (float)(L + 1);
    float cs = (s3 + EPS * rq[l] + EPS * (sumPKso + cwrk[l]) + EPS2) / nrm;
    sa[(size_t)bh * LSEQ + L] = fast_sigmoid(cs);
    float c2 = (s4 + EPS * rk[l] + EPS * (sumPQsi + cwrq[l]) + EPS2) / nrm;
    c2 = fminf(1.f, fmaxf(-1.f, c2));
    ebuf[(size_t)bh * LSEQ + L] = __expf(c2);
  }
}

// src_comp = e / cumsum(e) * (l+1)
__global__ __launch_bounds__(64) void srccomp_kernel(const float* __restrict__ ebuf, float* __restrict__ sc){
  int bh = blockIdx.x; int lane = threadIdx.x;
  const float* eb = ebuf + (size_t)bh * LSEQ;
  float loc[16]; float s = 0.f;
#pragma unroll
  for (int i = 0; i < 16; i++){ loc[i] = eb[lane * 16 + i]; s += loc[i]; }
  float run = wscan64(s, lane);
  float acc = run - s;
  float* scb = sc + (size_t)bh * LSEQ;
#pragma unroll
  for (int i = 0; i < 16; i++){
    acc += loc[i];
    scb[lane * 16 + i] = loc[i] / acc * (float)(lane * 16 + i + 1);
  }
}

// ---------------- chunked causal linear attention (scale fused in, bf16 S) ------
__global__ __launch_bounds__(256) void phaseA(const u16* __restrict__ k, const u16* __restrict__ v,
                                              const float* __restrict__ sc, u16* __restrict__ S){
  int blk = blockIdx.x; int bh = blk >> 4, c = blk & 15;
  if (c == 15) return;                 // chunk 15's S is never read (early exit)
  __shared__ float ks[64][68], vss[64][68];
  __shared__ float vc[64];
  int tid = threadIdx.x;
  size_t base = ((size_t)bh * LSEQ + c * 64) * DHD;
  const u16* kb = k + base; const u16* vb = v + base;
  if (tid < 64) vc[tid] = sc[(size_t)bh * LSEQ + c * 64 + tid];
  __syncthreads();
  for (int c4 = tid; c4 < 1024; c4 += 256){
    int l = c4 >> 4, d0 = (c4 & 15) * 4;
    ushort4 kv = *reinterpret_cast<const ushort4*>(kb + c4 * 4);
    ks[l][d0+0] = bf2f(kv.x); ks[l][d0+1] = bf2f(kv.y);
    ks[l][d0+2] = bf2f(kv.z); ks[l][d0+3] = bf2f(kv.w);
    ushort4 vv = *reinterpret_cast<const ushort4*>(vb + c4 * 4);
    float w = vc[l];
    vss[l][d0+0] = bf2f(vv.x) * w; vss[l][d0+1] = bf2f(vv.y) * w;
    vss[l][d0+2] = bf2f(vv.z) * w; vss[l][d0+3] = bf2f(vv.w) * w;
  }
  __syncthreads();
  int m = tid >> 2, dg = tid & 3;
  float acc[16] = {};
  for (int l = 0; l < 64; l++){
    float vm = vss[l][m];
#pragma unroll
    for (int d4 = 0; d4 < 4; d4++){
      float4 kk = *reinterpret_cast<const float4*>(&ks[l][dg * 16 + d4 * 4]);
      acc[d4*4+0] += vm * kk.x; acc[d4*4+1] += vm * kk.y;
      acc[d4*4+2] += vm * kk.z; acc[d4*4+3] += vm * kk.w;
    }
  }
  u16* Sb = S + (size_t)blk * 4096 + m * 64 + dg * 16;
#pragma unroll
  for (int d4 = 0; d4 < 4; d4++){
    ushort4 o;
    o.x = f2bf(acc[d4*4+0]); o.y = f2bf(acc[d4*4+1]);
    o.z = f2bf(acc[d4*4+2]); o.w = f2bf(acc[d4*4+3]);
    *reinterpret_cast<ushort4*>(Sb + d4 * 4) = o;
  }
}

// phase C with inlined KV-prefix (bf16 S); Ps overlays qsT (qrow cached first)
__global__ __launch_bounds__(256) void phaseC(const u16* __restrict__ q, const u16* __restrict__ k,
                                              const u16* __restrict__ v, const u16* __restrict__ S,
                                              const float* __restrict__ sink_in, const float* __restrict__ sc,
                                              const float* __restrict__ sa, u16* __restrict__ x){
  int blk = blockIdx.x; int bh = blk >> 4, c = blk & 15;
  int b = bh >> 4, h = bh & 15;
  __shared__ float qp[64][66];      // qsT[d][l] first, then Ps[l][j]
  __shared__ float kT[64][68];
  __shared__ float vss[64][68];
  __shared__ float kvs[64][68];
  __shared__ float qc[64], vc[64];
  int tid = threadIdx.x;
  size_t base = ((size_t)bh * LSEQ + c * 64) * DHD;
  const u16* qb = q + base; const u16* kb = k + base; const u16* vb = v + base;
  if (tid < 64){
    int L = c * 64 + tid;
    qc[tid] = sink_in[(size_t)bh * LSEQ + L] / (float)(L + 1);
    vc[tid] = sc[(size_t)bh * LSEQ + L];
  }
  // KV prefix: accumulate 16 bf16 elements per thread over chunks 0..c-1
  {
    int off16 = tid * 16;
    float accp[16] = {};
    for (int cc = 0; cc < c; cc++){
      size_t idx = ((size_t)bh * 16 + cc) * 4096 + off16;
#pragma unroll
      for (int t4 = 0; t4 < 4; t4++){
        ushort4 sv = *reinterpret_cast<const ushort4*>(S + idx + t4 * 4);
        accp[t4*4+0] += bf2f(sv.x); accp[t4*4+1] += bf2f(sv.y);
        accp[t4*4+2] += bf2f(sv.z); accp[t4*4+3] += bf2f(sv.w);
      }
    }
#pragma unroll
    for (int e = 0; e < 16; e++){
      int j = off16 + e;
      kvs[j >> 6][j & 63] = accp[e];
    }
  }
  __syncthreads();
  for (int c4 = tid; c4 < 1024; c4 += 256){
    int l = c4 >> 4, d0 = (c4 & 15) * 4;
    float qw = qc[l], vw = vc[l];
    ushort4 qv = *reinterpret_cast<const ushort4*>(qb + c4 * 4);
    qp[d0+0][l] = bf2f(qv.x) * qw; qp[d0+1][l] = bf2f(qv.y) * qw;
    qp[d0+2][l] = bf2f(qv.z) * qw; qp[d0+3][l] = bf2f(qv.w) * qw;
    ushort4 kv4 = *reinterpret_cast<const ushort4*>(kb + c4 * 4);
    kT[d0+0][l] = bf2f(kv4.x); kT[d0+1][l] = bf2f(kv4.y);
    kT[d0+2][l] = bf2f(kv4.z); kT[d0+3][l] = bf2f(kv4.w);
    ushort4 vv = *reinterpret_cast<const ushort4*>(vb + c4 * 4);
    vss[l][d0+0] = bf2f(vv.x) * vw; vss[l][d0+1] = bf2f(vv.y) * vw;
    vss[l][d0+2] = bf2f(vv.z) * vw; vss[l][d0+3] = bf2f(vv.w) * vw;
  }
  __syncthreads();
  int l = tid & 63, g = tid >> 6;
  float qrow[64];
#pragma unroll
  for (int d = 0; d < 64; d++) qrow[d] = qp[d][l];
  __syncthreads();

  float p[16] = {};
  for (int d = 0; d < 64; d++){
    float qv = qrow[d];
#pragma unroll
    for (int j4 = 0; j4 < 4; j4++){
      float4 kk = *reinterpret_cast<const float4*>(&kT[d][g * 16 + j4 * 4]);
      p[j4*4+0] += qv * kk.x; p[j4*4+1] += qv * kk.y;
      p[j4*4+2] += qv * kk.z; p[j4*4+3] += qv * kk.w;
    }
  }
#pragma unroll
  for (int jj = 0; jj < 16; jj++){
    int j = g * 16 + jj;
    qp[l][j] = (j <= l) ? p[jj] : 0.f;
  }
  __syncthreads();

  float acc[16];
#pragma unroll
  for (int mm = 0; mm < 16; mm++){
    float a = 0.f;
#pragma unroll
    for (int d4 = 0; d4 < 16; d4++){
      float4 kv4 = *reinterpret_cast<const float4*>(&kvs[g * 16 + mm][d4 * 4]);
      a += qrow[d4*4+0]*kv4.x + qrow[d4*4+1]*kv4.y + qrow[d4*4+2]*kv4.z + qrow[d4*4+3]*kv4.w;
    }
    acc[mm] = a;
  }
  for (int j = 0; j < 64; j++){
    float pv = qp[l][j];
#pragma unroll
    for (int m4 = 0; m4 < 4; m4++){
      float4 vv = *reinterpret_cast<const float4*>(&vss[j][g * 16 + m4 * 4]);
      acc[m4*4+0] += pv * vv.x; acc[m4*4+1] += pv * vv.y;
      acc[m4*4+2] += pv * vv.z; acc[m4*4+3] += pv * vv.w;
    }
  }
  float sav = sa[(size_t)bh * LSEQ + c * 64 + l];
  u16* xo = x + ((size_t)(b * 1024 + c * 64 + l)) * 1024 + h * 64 + g * 16;
#pragma unroll
  for (int mm = 0; mm < 16; mm++) xo[mm] = f2bf(acc[mm] * sav);
}

// ---------------- fused layernorms ----------------
// LN over (bf16 p0+p1 + bias + resid); emits f32 + bf16 (Wo split-K + LN1)
__global__ __launch_bounds__(256) void ln_fused2b(
    const u16* __restrict__ p0, const u16* __restrict__ p1,
    const float* __restrict__ resid, const float* __restrict__ bias,
    const float* __restrict__ g, const float* __restrict__ b,
    float* __restrict__ out, u16* __restrict__ outbf){
  int row = blockIdx.x; int tid = threadIdx.x;
  int lane = tid & 63, wave = tid >> 6;
  size_t off = (size_t)row * 1024 + tid * 4;
  ushort4 a0 = *reinterpret_cast<const ushort4*>(p0 + off);
  ushort4 a1 = *reinterpret_cast<const ushort4*>(p1 + off);
  float4 rr = *reinterpret_cast<const float4*>(resid + off);
  float4 bb = *reinterpret_cast<const float4*>(bias + tid * 4);
  float4 v = make_float4(bf2f(a0.x) + bf2f(a1.x) + rr.x + bb.x,
                         bf2f(a0.y) + bf2f(a1.y) + rr.y + bb.y,
                         bf2f(a0.z) + bf2f(a1.z) + rr.z + bb.z,
                         bf2f(a0.w) + bf2f(a1.w) + rr.w + bb.w);
  float s = v.x + v.y + v.z + v.w;
  float s2 = v.x*v.x + v.y*v.y + v.z*v.z + v.w*v.w;
  s = wred64(s); s2 = wred64(s2);
  __shared__ float red[2][4];
  if (lane == 0){ red[0][wave] = s; red[1][wave] = s2; }
  __syncthreads();
  float S = red[0][0] + red[0][1] + red[0][2] + red[0][3];
  float S2 = red[1][0] + red[1][1] + red[1][2] + red[1][3];
  float mean = S * (1.f / 1024.f);
  float var = S2 * (1.f / 1024.f) - mean * mean;
  float inv = rsqrtf(var + 1e-5f);
  float4 gv = *reinterpret_cast<const float4*>(g + tid * 4);
  float4 bv = *reinterpret_cast<const float4*>(b + tid * 4);
  float y0 = (v.x - mean) * inv * gv.x + bv.x;
  float y1 = (v.y - mean) * inv * gv.y + bv.y;
  float y2 = (v.z - mean) * inv * gv.z + bv.z;
  float y3 = (v.w - mean) * inv * gv.w + bv.w;
  *reinterpret_cast<float4*>(out + off) = make_float4(y0, y1, y2, y3);
  ushort4 o; o.x = f2bf(y0); o.y = f2bf(y1); o.z = f2bf(y2); o.w = f2bf(y3);
  *reinterpret_cast<ushort4*>(outbf + off) = o;
}

// LN over (bf16 p0..p3 + bias + resid) -> f32 out (FFN2 split-K4 combine + LN2)
__global__ __launch_bounds__(256) void ln_fused4b(
    const u16* __restrict__ p0, const u16* __restrict__ p1,
    const u16* __restrict__ p2, const u16* __restrict__ p3,
    const float* __restrict__ resid, const float* __restrict__ bias,
    const float* __restrict__ g, const float* __restrict__ b,
    float* __restrict__ out){
  int row = blockIdx.x; int tid = threadIdx.x;
  int lane = tid & 63, wave = tid >> 6;
  size_t off = (size_t)row * 1024 + tid * 4;
  ushort4 u0 = *reinterpret_cast<const ushort4*>(p0 + off);
  ushort4 u1 = *reinterpret_cast<const ushort4*>(p1 + off);
  ushort4 u2 = *reinterpret_cast<const ushort4*>(p2 + off);
  ushort4 u3 = *reinterpret_cast<const ushort4*>(p3 + off);
  float4 rr = *reinterpret_cast<const float4*>(resid + off);
  float4 bb = *reinterpret_cast<const float4*>(bias + tid * 4);
  float4 v = make_float4(
      bf2f(u0.x) + bf2f(u1.x) + bf2f(u2.x) + bf2f(u3.x) + rr.x + bb.x,
      bf2f(u0.y) + bf2f(u1.y) + bf2f(u2.y) + bf2f(u3.y) + rr.y + bb.y,
      bf2f(u0.z) + bf2f(u1.z) + bf2f(u2.z) + bf2f(u3.z) + rr.z + bb.z,
      bf2f(u0.w) + bf2f(u1.w) + bf2f(u2.w) + bf2f(u3.w) + rr.w + bb.w);
  float s = v.x + v.y + v.z + v.w;
  float s2 = v.x*v.x + v.y*v.y + v.z*v.z + v.w*v.w;
  s = wred64(s); s2 = wred64(s2);
  __shared__ float red[2][4];
  if (lane == 0){ red[0][wave] = s; red[1][wave] = s2; }
  __syncthreads();
  float S = red[0][0] + red[0][1] + red[0][2] + red[0][3];
  float S2 = red[1][0] + red[1][1] + red[1][2] + red[1][3];
  float mean = S * (1.f / 1024.f);
  float var = S2 * (1.f / 1024.f) - mean * mean;
  float inv = rsqrtf(var + 1e-5f);
  float4 gv = *reinterpret_cast<const float4*>(g + tid * 4);
  float4 bv = *reinterpret_cast<const float4*>(b + tid * 4);
  float y0 = (v.x - mean) * inv * gv.x + bv.x;
  float y1 = (v.y - mean) * inv * gv.y + bv.y;
  float y2 = (v.z - mean) * inv * gv.z + bv.z;
  float y3 = (v.w - mean) * inv * gv.w + bv.w;
  *reinterpret_cast<float4*>(out + off) = make_float4(y0, y1, y2, y3);
}

// ---------------- launch ----------------
extern "C" void kernel_launch(void* const* d_in, const int* in_sizes, int n_in,
                              void* d_out, int out_size, void* d_ws, size_t ws_size,
                              hipStream_t stream){
  (void)in_sizes; (void)n_in; (void)out_size; (void)ws_size;
  const float* inputs = (const float*)d_in[0];
  const float* Wq = (const float*)d_in[2];  const float* bq = (const float*)d_in[3];
  const float* Wk = (const float*)d_in[4];  const float* bk = (const float*)d_in[5];
  const float* Wv = (const float*)d_in[6];  const float* bv = (const float*)d_in[7];
  const float* Wo = (const float*)d_in[8];  const float* bo = (const float*)d_in[9];
  const float* ln1g = (const float*)d_in[10]; const float* ln1b = (const float*)d_in[11];
  const float* W1 = (const float*)d_in[12]; const float* b1 = (const float*)d_in[13];
  const float* W2 = (const float*)d_in[14]; const float* b2 = (const float*)d_in[15];
  const float* ln2g = (const float*)d_in[16]; const float* ln2b = (const float*)d_in[17];
  float* out = (float*)d_out;

  char* wsp = (char*)d_ws; size_t off = 0;
  auto alloc = [&](size_t bytes) -> void* {
    off = (off + 255) & ~(size_t)255;
    void* p = wsp + off; off += bytes; return p;
  };
  const size_t MD = (size_t)2048 * 1024;
  u16* Xbf    = (u16*)alloc(MD * 2);
  u16* WqkvT  = (u16*)alloc((size_t)3 * 1024 * 1024 * 2);
  u16* WoT    = (u16*)alloc((size_t)1024 * 1024 * 2);
  u16* W1T    = (u16*)alloc((size_t)4096 * 1024 * 2);
  u16* W2T    = (u16*)alloc((size_t)4096 * 1024 * 2);
  float* bqkv = (float*)alloc(3072 * 4);
  u16* qkvb   = (u16*)alloc(3 * MD * 2);     // bf16 q|k|v in [B,H,L,DH]
  u16* qb = qkvb; u16* kb = qkvb + MD; u16* vb = qkvb + 2 * MD;
  float* quad = (float*)alloc(4 * MD * 4);
  u16* Sbuf   = (u16*)quad;                  // bf16 S: 512 x 4096 x 2B = 4MB
  float* ckb  = (float*)alloc((size_t)512 * 64 * 4);   // contiguous with cqb
  float* cqb  = (float*)alloc((size_t)512 * 64 * 4);
  float* csob = (float*)alloc((size_t)512 * 64 * 4);
  float* cqsib= (float*)alloc((size_t)512 * 64 * 4);
  float* sink_in = (float*)alloc(NBH * LSEQ * 4);
  float* src_out = (float*)alloc(NBH * LSEQ * 4);
  float* sabuf   = (float*)alloc(NBH * LSEQ * 4);
  float* ebuf    = (float*)alloc(NBH * LSEQ * 4);
  float* scbuf   = (float*)alloc(NBH * LSEQ * 4);
  u16* xatt   = (u16*)alloc(MD * 2);
  u16* g1     = (u16*)alloc((size_t)2048 * 4096 * 2);
  // quad reuse: slot0 Sbuf(bf16,4MB) -> hbuf (f32 LN1 out, 8MB); slot1 hbf (bf16);
  // slots2-3: Wo bf16 partials (8MB) then FFN2 bf16 partials (16MB)
  float* hbuf  = quad;
  u16* hbf     = (u16*)(quad + MD);
  u16* wopart  = (u16*)(quad + 2 * MD);
  u16* partb   = (u16*)(quad + 2 * MD);

  // all prep in one launch (+64 blocks zeroing ckb||cqb)
  prep_all<<<14412, 256, 0, stream>>>(inputs, Xbf, Wq, Wk, Wv, Wo, WqkvT, WoT,
                                      W1, W2, W1T, W2T, bq, bk, bv, bqkv, ckb);

  // fused QKV projection (bf16 out) + chunk-sum atomics: BM=128,BN=64, grid 16x48
  gemm_mfma<128, 64, 0, 1><<<dim3(16, 48), 256, 0, stream>>>(
      Xbf, WqkvT, bqkv, nullptr, nullptr, qkvb, cqb, ckb, 2048, 3072, 1024);

  // attention scalars (chunked Gram-tile pipeline, bf16 inputs)
  sink_tile<<<512, 256, 0, stream>>>(qb, kb, ckb, cqb, sink_in, src_out, csob, cqsib);
  cons_tile<<<512, 256, 0, stream>>>(qb, kb, csob, cqsib, sink_in, src_out, sabuf, ebuf);
  srccomp_kernel<<<32, 64, 0, stream>>>(ebuf, scbuf);

  // chunked causal linear attention (scale fused; bf16 S; KV-prefix in phaseC)
  phaseA<<<512, 256, 0, stream>>>(kb, vb, scbuf, Sbuf);
  phaseC<<<512, 256, 0, stream>>>(qb, kb, vb, Sbuf, sink_in, scbuf, sabuf, xatt);

  // output projection: BM=128,BN=64, split-K=2, bf16 partials
  gemm_mfma<128, 64, 0, 5><<<dim3(16, 16, 2), 256, 0, stream>>>(
      xatt, WoT, nullptr, nullptr, nullptr, wopart, nullptr, nullptr, 2048, 1024, 1024);
  ln_fused2b<<<2048, 256, 0, stream>>>(wopart, wopart + MD, inputs, bo, ln1g, ln1b, hbuf, hbf);

  // FFN1: BM=128,BN=128 (fast gelu)
  gemm_mfma<128, 128, 2, 3><<<dim3(16, 32), 256, 0, stream>>>(
      hbf, W1T, b1, nullptr, nullptr, g1, nullptr, nullptr, 2048, 4096, 1024);
  // FFN2: BM=128,BN=128, split-K=4, bf16 partials
  gemm_mfma<128, 128, 0, 5><<<dim3(16, 8, 4), 256, 0, stream>>>(
      g1, W2T, nullptr, nullptr, nullptr, partb, nullptr, nullptr, 2048, 1024, 4096);
  ln_fused4b<<<2048, 256, 0, stream>>>(partb, partb + MD, partb + 2 * MD, partb + 3 * MD,
                                       hbuf, b2, ln2g, ln2b, out);
}